// Round 11
// baseline (259.029 us; speedup 1.0000x reference)
//
#include <hip/hip_runtime.h>
#include <math.h>

#define BB 16
#define NP 8192
#define NV 42
#define NF 80
#define FEAT 256
#define WJS 129          // padded LDS stride (129%32==1 -> conflict-free everywhere)

__device__ __forceinline__ float rcp_f(float x)  { return __builtin_amdgcn_rcpf(x); }
__device__ __forceinline__ float rsq_f(float x)  { return __builtin_amdgcn_rsqf(x); }
__device__ __forceinline__ float sqrt_f(float x) { return __builtin_amdgcn_sqrtf(x); }

// theta = 2*asin(x), x in [0,1). Branchless, |err|~1e-5. (validated r2-r10)
__device__ __forceinline__ float theta_from_x(float x) {
  bool big = x > 0.5f;
  float z = big ? fmaf(-0.5f, x, 0.5f) : x * x;
  float s = big ? sqrt_f(z) : x;
  float P = fmaf(z, 0.022371875f, 0.030381944f);
  P = fmaf(z, P, 0.044642857f);
  P = fmaf(z, P, 0.075f);
  P = fmaf(z, P, 0.16666667f);
  float r = fmaf(s * z, P, s);
  return big ? fmaf(-4.f, r, 3.14159265358979f) : 2.f * r;
}

// ---- 2-wide float pair: forces two independent chains per thread ----
struct f2 { float x, y; };
__device__ __forceinline__ f2 mkf2(float a, float b) { f2 r; r.x = a; r.y = b; return r; }
__device__ __forceinline__ f2 f2add(f2 a, f2 b) { return mkf2(a.x + b.x, a.y + b.y); }
__device__ __forceinline__ f2 f2sub(f2 a, f2 b) { return mkf2(a.x - b.x, a.y - b.y); }
__device__ __forceinline__ f2 f2subs(float s, f2 b) { return mkf2(s - b.x, s - b.y); }
__device__ __forceinline__ f2 f2mul(f2 a, f2 b) { return mkf2(a.x * b.x, a.y * b.y); }
__device__ __forceinline__ f2 f2muls(float s, f2 a) { return mkf2(s * a.x, s * a.y); }
__device__ __forceinline__ f2 f2fma(f2 a, f2 b, f2 c) {
  return mkf2(fmaf(a.x, b.x, c.x), fmaf(a.y, b.y, c.y));
}
__device__ __forceinline__ f2 f2neg(f2 a) { return mkf2(-a.x, -a.y); }
__device__ __forceinline__ f2 f2rsq(f2 a) { return mkf2(rsq_f(a.x), rsq_f(a.y)); }
__device__ __forceinline__ f2 f2rcp(f2 a) { return mkf2(rcp_f(a.x), rcp_f(a.y)); }
__device__ __forceinline__ f2 f2sqrt(f2 a) { return mkf2(sqrt_f(a.x), sqrt_f(a.y)); }
__device__ __forceinline__ f2 f2clampx(f2 a) {   // reference l>=2 clamp
  return mkf2(a.x >= 1.f ? 0.99999f : a.x, a.y >= 1.f ? 0.99999f : a.y);
}
__device__ __forceinline__ f2 f2cx(f2 x) {       // sqrt(max(1-x^2,0))
  return mkf2(sqrt_f(fmaxf(fmaf(-x.x, x.x, 1.f), 0.f)),
              sqrt_f(fmaxf(fmaf(-x.y, x.y, 1.f), 0.f)));
}
__device__ __forceinline__ f2 f2sq1mc(f2 c) {    // sqrt(1-c^2), c pre-clamped
  return mkf2(sqrt_f(fmaf(-c.x, c.x, 1.f)), sqrt_f(fmaf(-c.y, c.y, 1.f)));
}
__device__ __forceinline__ f2 f2theta(f2 x) {
  return mkf2(theta_from_x(x.x), theta_from_x(x.y));
}
__device__ __forceinline__ f2 f2clampc(f2 c) {
  return mkf2(fminf(fmaxf(c.x, -0.99999f), 0.99999f),
              fminf(fmaxf(c.y, -0.99999f), 0.99999f));
}
__device__ __forceinline__ f2 f2sign(f2 d) {
  return mkf2((d.x > 0.f) ? 1.f : ((d.x < 0.f) ? -1.f : 0.f),
              (d.y > 0.f) ? 1.f : ((d.y < 0.f) ? -1.f : 0.f));
}

// cold path: runtime face recompute, inside-formula accumulate into own column
__device__ __attribute__((noinline)) void inside_face_rt(
    int f0, int f1, int f2i, const float4* vpos,
    float qx, float qy, float qz, float* wjh)
{
  float4 v0 = vpos[f0], v1 = vpos[f1], v2 = vpos[f2i];
  float a0x = v0.x - qx, a0y = v0.y - qy, a0z = v0.z - qz;
  float a1x = v1.x - qx, a1y = v1.y - qy, a1z = v1.z - qz;
  float a2x = v2.x - qx, a2y = v2.y - qy, a2z = v2.z - qz;
  float ss0 = fmaf(a0x, a0x, fmaf(a0y, a0y, a0z * a0z));
  float ss1 = fmaf(a1x, a1x, fmaf(a1y, a1y, a1z * a1z));
  float ss2 = fmaf(a2x, a2x, fmaf(a2y, a2y, a2z * a2z));
  float i0 = rsq_f(ss0), i1 = rsq_f(ss1), i2 = rsq_f(ss2);
  float d0 = ss0 * i0, d1 = ss1 * i1, d2 = ss2 * i2;
  float u0x = a0x * i0, u0y = a0y * i0, u0z = a0z * i0;
  float u1x = a1x * i1, u1y = a1y * i1, u1z = a1z * i1;
  float u2x = a2x * i2, u2y = a2y * i2, u2z = a2z * i2;
  float ex = u1x - u2x, ey = u1y - u2y, ez = u1z - u2z;
  float x0 = 0.5f * sqrt_f(fmaf(ex, ex, fmaf(ey, ey, ez * ez)));
  ex = u2x - u0x; ey = u2y - u0y; ez = u2z - u0z;
  float x1 = 0.5f * sqrt_f(fmaf(ex, ex, fmaf(ey, ey, ez * ez)));
  ex = u0x - u1x; ey = u0y - u1y; ez = u0z - u1z;
  float x2 = 0.5f * sqrt_f(fmaf(ex, ex, fmaf(ey, ey, ez * ez)));
  if (x0 >= 1.f) x0 = 0.99999f;
  if (x1 >= 1.f) x1 = 0.99999f;
  if (x2 >= 1.f) x2 = 0.99999f;
  float th0 = theta_from_x(x0), th1 = theta_from_x(x1), th2 = theta_from_x(x2);
  float hh = 0.5f * ((th0 + th1) + th2);
  if (3.14159265358979f - hh < 1e-4f) {
    float cx0 = sqrt_f(fmaxf(fmaf(-x0, x0, 1.f), 0.f));
    float cx1 = sqrt_f(fmaxf(fmaf(-x1, x1, 1.f), 0.f));
    float cx2 = sqrt_f(fmaxf(fmaf(-x2, x2, 1.f), 0.f));
    wjh[f0 * WJS]  += (2.f * (x0 * cx0) * d2) * d1;
    wjh[f1 * WJS]  += (2.f * (x1 * cx1) * d0) * d2;
    wjh[f2i * WJS] += (2.f * (x2 * cx2) * d1) * d0;
  }
}

// ---------------- Kernel D: MVC weights + deformed ----------------
// 128 threads = 2 waves; each THREAD owns 2 points (A = lane, B = lane+64 of
// its wave's 128-point range) computed as f2 pairs -> guaranteed dual chains.
__global__ __launch_bounds__(128) void mvc_kernel(
    const float* __restrict__ src,      // (B,3,N)
    const float* __restrict__ cage_t,   // (B,42,3)
    const float* __restrict__ ncage_t,  // (B,42,3)
    const int* __restrict__ faces,      // (80,3)
    float* __restrict__ out_def,        // (B,3,N)
    float* __restrict__ out_w)          // (B,N,42)
{
  __shared__ float4 vpos[NV];
  __shared__ float4 npos[NV];
  __shared__ int fidp[NF];
  __shared__ float wj[2][NV * WJS];

  const float PI_F = 3.14159265358979323846f;
  int tid  = threadIdx.x;
  int lane = tid & 63;
  int wv   = tid >> 6;
  int b    = blockIdx.x / (NP / 256);
  int pblk = blockIdx.x % (NP / 256);
  int gpA  = pblk * 256 + wv * 128 + lane;
  int gpB  = gpA + 64;

  if (tid < NV) {
    const float* cp = cage_t + (size_t)b * NV * 3 + tid * 3;
    vpos[tid] = make_float4(cp[0], cp[1], cp[2], 0.f);
    const float* np_ = ncage_t + (size_t)b * NV * 3 + tid * 3;
    npos[tid] = make_float4(np_[0], np_[1], np_[2], 0.f);
  }
  if (tid < NF) {
    int f0 = faces[3 * tid], f1 = faces[3 * tid + 1], f2i = faces[3 * tid + 2];
    fidp[tid] = f0 | (f1 << 6) | (f2i << 12);
  }
  for (int i = tid; i < 2 * NV * WJS; i += 128) wj[0][i] = 0.f;
  __syncthreads();

  f2 qx = mkf2(src[(size_t)b * 3 * NP + gpA],          src[(size_t)b * 3 * NP + gpB]);
  f2 qy = mkf2(src[(size_t)b * 3 * NP + NP + gpA],     src[(size_t)b * 3 * NP + NP + gpB]);
  f2 qz = mkf2(src[(size_t)b * 3 * NP + 2 * NP + gpA], src[(size_t)b * 3 * NP + 2 * NP + gpB]);

  int inA = 0, inB = 0;
  unsigned long long clA = 0ull, clB = 0ull;
  float* wjA = &wj[wv][lane];
  float* wjB = wjA + 64;

  #pragma unroll 1
  for (int i = 0; i < NF; i++) {
    int pk = fidp[i];
    int f0 = pk & 63, f1 = (pk >> 6) & 63, f2i = pk >> 12;
    float4 v0 = vpos[f0], v1 = vpos[f1], v2 = vpos[f2i];
    f2 a0x = f2subs(v0.x, qx), a0y = f2subs(v0.y, qy), a0z = f2subs(v0.z, qz);
    f2 a1x = f2subs(v1.x, qx), a1y = f2subs(v1.y, qy), a1z = f2subs(v1.z, qz);
    f2 a2x = f2subs(v2.x, qx), a2y = f2subs(v2.y, qy), a2z = f2subs(v2.z, qz);
    f2 ss0 = f2fma(a0x, a0x, f2fma(a0y, a0y, f2mul(a0z, a0z)));
    f2 ss1 = f2fma(a1x, a1x, f2fma(a1y, a1y, f2mul(a1z, a1z)));
    f2 ss2 = f2fma(a2x, a2x, f2fma(a2y, a2y, f2mul(a2z, a2z)));
    if (ss0.x < 1e-16f) clA |= (1ull << f0);
    if (ss1.x < 1e-16f) clA |= (1ull << f1);
    if (ss2.x < 1e-16f) clA |= (1ull << f2i);
    if (ss0.y < 1e-16f) clB |= (1ull << f0);
    if (ss1.y < 1e-16f) clB |= (1ull << f1);
    if (ss2.y < 1e-16f) clB |= (1ull << f2i);
    f2 i0 = f2rsq(ss0), i1 = f2rsq(ss1), i2 = f2rsq(ss2);
    f2 d0 = f2mul(ss0, i0), d1 = f2mul(ss1, i1), d2 = f2mul(ss2, i2);
    f2 u0x = f2mul(a0x, i0), u0y = f2mul(a0y, i0), u0z = f2mul(a0z, i0);
    f2 u1x = f2mul(a1x, i1), u1y = f2mul(a1y, i1), u1z = f2mul(a1z, i1);
    f2 u2x = f2mul(a2x, i2), u2y = f2mul(a2y, i2), u2z = f2mul(a2z, i2);
    // chord half-lengths via EDGE SUBTRACTION (r7 lesson: never 1-u.u')
    f2 ex = f2sub(u1x, u2x), ey = f2sub(u1y, u2y), ez = f2sub(u1z, u2z);
    f2 x0 = f2muls(0.5f, f2sqrt(f2fma(ex, ex, f2fma(ey, ey, f2mul(ez, ez)))));
    ex = f2sub(u2x, u0x); ey = f2sub(u2y, u0y); ez = f2sub(u2z, u0z);
    f2 x1 = f2muls(0.5f, f2sqrt(f2fma(ex, ex, f2fma(ey, ey, f2mul(ez, ez)))));
    ex = f2sub(u0x, u1x); ey = f2sub(u0y, u1y); ez = f2sub(u0z, u1z);
    f2 x2 = f2muls(0.5f, f2sqrt(f2fma(ex, ex, f2fma(ey, ey, f2mul(ez, ez)))));
    x0 = f2clampx(x0); x1 = f2clampx(x1); x2 = f2clampx(x2);
    f2 cx0 = f2cx(x0), cx1 = f2cx(x1), cx2 = f2cx(x2);
    f2 th0 = f2theta(x0), th1 = f2theta(x1), th2 = f2theta(x2);
    f2 hh = f2muls(0.5f, f2add(f2add(th0, th1), th2));
    if (PI_F - hh.x < 1e-4f) inA = 1;
    if (PI_F - hh.y < 1e-4f) inB = 1;
    f2 t0 = f2mul(x0, cx0), t1 = f2mul(x1, cx1), t2 = f2mul(x2, cx2);
    f2 st0 = f2add(t0, t0), st1 = f2add(t1, t1), st2 = f2add(t2, t2);
    f2 A1 = f2mul(x0, f2mul(cx1, cx2));
    f2 A2 = f2mul(x1, f2mul(cx0, cx2));
    f2 A3 = f2mul(x2, f2mul(cx0, cx1));
    f2 A4 = f2mul(x0, f2mul(x1, x2));
    f2 sh  = f2sub(f2add(f2add(A1, A2), A3), A4);       // sin(h)
    f2 sm0 = f2add(f2add(f2sub(A2, A1), A3), A4);       // sin(h-th0)
    f2 sm1 = f2add(f2add(f2sub(A1, A2), A3), A4);       // sin(h-th1)
    f2 sm2 = f2add(f2sub(f2add(A1, A2), A3), A4);       // sin(h-th2)
    f2 twosh = f2add(sh, sh);
    f2 none = mkf2(-1.f, -1.f);
    f2 c0 = f2fma(f2mul(twosh, sm0), f2rcp(f2mul(st1, st2)), none);
    f2 c1 = f2fma(f2mul(twosh, sm1), f2rcp(f2mul(st2, st0)), none);
    f2 c2 = f2fma(f2mul(twosh, sm2), f2rcp(f2mul(st0, st1)), none);
    c0 = f2clampc(c0); c1 = f2clampc(c1); c2 = f2clampc(c2);
    f2 m0 = f2fma(u1y, u2z, f2neg(f2mul(u1z, u2y)));
    f2 m1 = f2fma(u1x, u2z, f2neg(f2mul(u1z, u2x)));
    f2 m2 = f2fma(u1x, u2y, f2neg(f2mul(u1y, u2x)));
    f2 det = f2add(f2sub(f2mul(u0x, m0), f2mul(u0y, m1)), f2mul(u0z, m2));
    f2 sg = f2sign(det);
    f2 sn0 = f2mul(sg, f2sq1mc(c0));
    f2 sn1 = f2mul(sg, f2sq1mc(c1));
    f2 sn2 = f2mul(sg, f2sq1mc(c2));
    f2 w0 = f2mul(f2fma(f2neg(c2), th1, f2fma(f2neg(c1), th2, th0)),
                  f2rcp(f2mul(f2mul(d0, st1), sn2)));
    f2 w1 = f2mul(f2fma(f2neg(c0), th2, f2fma(f2neg(c2), th0, th1)),
                  f2rcp(f2mul(f2mul(d1, st2), sn0)));
    f2 w2 = f2mul(f2fma(f2neg(c1), th0, f2fma(f2neg(c0), th1, th2)),
                  f2rcp(f2mul(f2mul(d2, st0), sn1)));
    wjA[f0 * WJS]  += w0.x;  wjB[f0 * WJS]  += w0.y;
    wjA[f1 * WJS]  += w1.x;  wjB[f1 * WJS]  += w1.y;
    wjA[f2i * WJS] += w2.x;  wjB[f2i * WJS] += w2.y;
  }

  // cold paths (per point, scalar)
  if (inA) {
    for (int c = 0; c < NV; c++) wjA[c * WJS] = 0.f;
    for (int i = 0; i < NF; i++) {
      int pk = fidp[i];
      inside_face_rt(pk & 63, (pk >> 6) & 63, pk >> 12, vpos, qx.x, qy.x, qz.x, wjA);
    }
  }
  if (inB) {
    for (int c = 0; c < NV; c++) wjB[c * WJS] = 0.f;
    for (int i = 0; i < NF; i++) {
      int pk = fidp[i];
      inside_face_rt(pk & 63, (pk >> 6) & 63, pk >> 12, vpos, qx.y, qy.y, qz.y, wjB);
    }
  }

  // per-point epilogue (own wave's LDS region; no barrier needed)
  auto finish = [&](float* wjh, unsigned long long mCl, int gp) {
    float sum = 0.f;
    if (mCl) {   // cold: query coincides with a cage vertex
      for (int c = 0; c < NV; c++) {
        float w = ((mCl >> c) & 1ull) ? 1.f : 0.f;
        wjh[c * WJS] = w;
        sum += w;
      }
    } else {
      for (int c = 0; c < NV; c++) sum += wjh[c * WJS];
    }
    if (sum == 0.f) sum = 1.f;
    float inv = rcp_f(sum);
    float ax = 0.f, ay = 0.f, az = 0.f;
    for (int c = 0; c < NV; c++) {
      float w = wjh[c * WJS] * inv;
      wjh[c * WJS] = w;
      float4 n = npos[c];
      ax = fmaf(w, n.x, ax);
      ay = fmaf(w, n.y, ay);
      az = fmaf(w, n.z, az);
    }
    out_def[(size_t)b * 3 * NP + gp]          = ax;
    out_def[(size_t)b * 3 * NP + NP + gp]     = ay;
    out_def[(size_t)b * 3 * NP + 2 * NP + gp] = az;
  };
  finish(wjA, clA, gpA);
  finish(wjB, clB, gpB);
  __syncthreads();

  // coalesced weight write for all 256 points of the block
  float* wbase = out_w + ((size_t)b * NP + pblk * 256) * NV;
  for (int idx = tid; idx < 256 * NV; idx += 128) {
    int pp = idx / NV;
    int c  = idx - pp * NV;
    wbase[idx] = wj[pp >> 7][c * WJS + (pp & 127)];
  }
}

// ---------------- shared split-K linear body (round-3 proven) ----------------
__device__ __forceinline__ void splitk_body(
    const float* in0, const float* in1,
    const float* W, const float* bias, float* out,
    int FI, int FO, int relu, int ox, int bb, int tid,
    float* sIn, float (*part)[64])
{
  for (int i = tid; i < FI; i += 256) {
    float v;
    if (in1) v = (i < FEAT) ? in0[(size_t)bb * FEAT + i]
                            : in1[(size_t)bb * FEAT + i - FEAT];
    else     v = in0[(size_t)bb * FI + i];
    sIn[i] = v;
  }
  __syncthreads();
  int o = ox * 64 + (tid & 63);
  int kk = tid >> 6;
  int seg = FI >> 2;
  float acc = 0.f;
  const float* wp = W + o;
  #pragma unroll 4
  for (int i = kk * seg; i < (kk + 1) * seg; i++)
    acc = fmaf(sIn[i], wp[(size_t)i * FO], acc);
  part[kk][tid & 63] = acc;
  __syncthreads();
  if (tid < 64) {
    float r = ((part[0][tid] + part[1][tid]) + (part[2][tid] + part[3][tid]))
              + bias[o];
    out[(size_t)bb * FO + o] = relu ? fmaxf(r, 0.f) : r;
  }
}

// ---------------- Kernel A: cage_opt (blocks<672) + L1 split-K (672..799) ----
__global__ __launch_bounds__(256) void cage_l1_kernel(
    const float* __restrict__ tmpl, const float* __restrict__ src,
    const float* __restrict__ sf, const float* __restrict__ tf,
    const float* __restrict__ W1, const float* __restrict__ b1,
    float* __restrict__ cage, float* __restrict__ h1)
{
  __shared__ float red[8];
  __shared__ float sIn[512];
  __shared__ float part[4][64];
  int tid = threadIdx.x;

  if (blockIdx.x < BB * NV) {
    int b = blockIdx.x / NV;
    int v = blockIdx.x % NV;
    const float* sp = src + (size_t)b * 3 * NP;
    float cx = tmpl[v], cy = tmpl[NV + v], cz = tmpl[2 * NV + v];
    int k = 0;
    while (true) {
      float m = 3.4e38f;
      for (int i = tid; i < NP; i += 256) {
        float dx = __fsub_rn(cx, sp[i]);
        float dy = __fsub_rn(cy, sp[NP + i]);
        float dz = __fsub_rn(cz, sp[2 * NP + i]);
        float ss = __fadd_rn(__fadd_rn(__fmul_rn(dx, dx), __fmul_rn(dy, dy)),
                             __fmul_rn(dz, dz));
        m = fminf(m, ss);
      }
      #pragma unroll
      for (int off = 32; off > 0; off >>= 1)
        m = fminf(m, __shfl_down(m, off, 64));
      int wid = tid >> 6;
      __syncthreads();
      if ((tid & 63) == 0) red[wid] = m;
      __syncthreads();
      if (tid == 0) {
        float mm = fminf(fminf(red[0], red[1]), fminf(red[2], red[3]));
        red[4] = sqrtf(mm);
      }
      __syncthreads();
      float mind = red[4];
      if (mind > 0.4f && k < 100) {
        cx = __fsub_rn(cx, __fmul_rn(0.01f, cx));
        cy = __fsub_rn(cy, __fmul_rn(0.01f, cy));
        cz = __fsub_rn(cz, __fmul_rn(0.01f, cz));
        k++;
      } else {
        break;
      }
    }
    if (tid == 0) {
      cage[(size_t)b * 3 * NV + v]          = cx;
      cage[(size_t)b * 3 * NV + NV + v]     = cy;
      cage[(size_t)b * 3 * NV + 2 * NV + v] = cz;
    }
  } else {
    int idx = blockIdx.x - BB * NV;   // 0..127
    splitk_body(sf, tf, W1, b1, h1, 512, 512, 1, idx & 7, idx >> 3,
                tid, sIn, part);
  }
}

// ---------------- standalone split-K linear (round-3 proven) ----------------
__global__ __launch_bounds__(256) void linear_splitk(
    const float* __restrict__ in0, const float* __restrict__ in1,
    const float* __restrict__ W, const float* __restrict__ bias,
    float* __restrict__ out, int FI, int FO, int relu)
{
  __shared__ float sIn[512];
  __shared__ float part[4][64];
  splitk_body(in0, in1, W, bias, out, FI, FO, relu,
              blockIdx.x, blockIdx.y, threadIdx.x, sIn, part);
}

// ---------------- L4 + cage finalize (round-3 proven) ----------------
__global__ __launch_bounds__(128) void l4_finalize_kernel(
    const float* __restrict__ h3,
    const float* __restrict__ W4, const float* __restrict__ b4,
    const float* __restrict__ cage,
    float* __restrict__ out_io,
    float* __restrict__ cage_t,
    float* __restrict__ ncage_t)
{
  __shared__ float sIn[256];
  int bb = blockIdx.x;
  int tid = threadIdx.x;
  sIn[tid] = h3[(size_t)bb * 256 + tid];
  sIn[tid + 128] = h3[(size_t)bb * 256 + tid + 128];
  __syncthreads();
  if (tid < 126) {
    float acc = b4[tid];
    const float* wp = W4 + tid;
    #pragma unroll 4
    for (int i = 0; i < 256; i++) acc = fmaf(sIn[i], wp[(size_t)i * 126], acc);
    out_io[(size_t)bb * 126 + tid] = acc;
    float c  = cage[(size_t)bb * 126 + tid];
    float nc = c + acc;
    int d = tid / NV, v = tid - d * NV;
    cage_t[(size_t)bb * NV * 3 + v * 3 + d]  = c;
    ncage_t[(size_t)bb * NV * 3 + v * 3 + d] = nc;
  }
}

extern "C" void kernel_launch(void* const* d_in, const int* in_sizes, int n_in,
                              void* d_out, int out_size, void* d_ws, size_t ws_size,
                              hipStream_t stream) {
  (void)in_sizes; (void)n_in; (void)out_size; (void)d_ws; (void)ws_size;
  const float* src   = (const float*)d_in[0];
  const float* sf    = (const float*)d_in[2];
  const float* tf    = (const float*)d_in[3];
  const float* tmpl  = (const float*)d_in[4];
  const int*   faces = (const int*)d_in[5];
  const float* W1 = (const float*)d_in[6];  const float* b1 = (const float*)d_in[7];
  const float* W2 = (const float*)d_in[8];  const float* b2 = (const float*)d_in[9];
  const float* W3 = (const float*)d_in[10]; const float* b3 = (const float*)d_in[11];
  const float* W4 = (const float*)d_in[12]; const float* b4 = (const float*)d_in[13];

  float* out = (float*)d_out;
  float* out_cage_t  = out;                 // (16,42,3)   2016
  float* out_ncage_t = out + 2016;          // (16,42,3)   2016
  float* out_def     = out + 4032;          // (16,3,8192) 393216
  float* out_w       = out + 397248;        // (16,8192,42) 5505024
  float* out_io      = out + 5902272;       // (16,126)    2016

  // scratch carved out of the weights region (fully overwritten by mvc_kernel)
  float* s_cage = out_w;           // 2016
  float* s_h1   = out_w + 2016;    // 8192
  float* s_h2   = out_w + 10208;   // 8192
  float* s_h3   = out_w + 18400;   // 4096

  cage_l1_kernel<<<dim3(BB * NV + 128), dim3(256), 0, stream>>>(
      tmpl, src, sf, tf, W1, b1, s_cage, s_h1);
  linear_splitk<<<dim3(8, BB), dim3(256), 0, stream>>>(s_h1, nullptr, W2, b2, s_h2, 512, 512, 1);
  linear_splitk<<<dim3(4, BB), dim3(256), 0, stream>>>(s_h2, nullptr, W3, b3, s_h3, 512, 256, 1);
  l4_finalize_kernel<<<dim3(BB), dim3(128), 0, stream>>>(
      s_h3, W4, b4, s_cage, out_io, out_cage_t, out_ncage_t);
  mvc_kernel<<<dim3(BB * (NP / 256)), dim3(128), 0, stream>>>(
      src, out_cage_t, out_ncage_t, faces, out_def, out_w);
}

// Round 12
// 183.324 us; speedup vs baseline: 1.4130x; 1.4130x over previous
//
#include <hip/hip_runtime.h>
#include <math.h>

#define BB 16
#define NP 8192
#define NV 42
#define NF 80
#define FEAT 256
#define WJS 131          // odd stride: conflict-free hot loop AND transposed epilogue

typedef float v2f __attribute__((ext_vector_type(2)));

__device__ __forceinline__ float rcp_f(float x)  { return __builtin_amdgcn_rcpf(x); }
__device__ __forceinline__ float rsq_f(float x)  { return __builtin_amdgcn_rsqf(x); }
__device__ __forceinline__ float sqrt_f(float x) { return __builtin_amdgcn_sqrtf(x); }

__device__ __forceinline__ v2f mk2(float s) { return (v2f){s, s}; }
__device__ __forceinline__ v2f v2fma(v2f a, v2f b, v2f c) {
  return __builtin_elementwise_fma(a, b, c);
}
__device__ __forceinline__ v2f v2sqrt(v2f a) {
  return (v2f){sqrt_f(a.x), sqrt_f(a.y)};
}
__device__ __forceinline__ v2f v2rsq(v2f a) {
  return (v2f){rsq_f(a.x), rsq_f(a.y)};
}
__device__ __forceinline__ v2f v2rcp(v2f a) {
  return (v2f){rcp_f(a.x), rcp_f(a.y)};
}
__device__ __forceinline__ v2f v2max0(v2f a) {          // max(a,0)
  return __builtin_elementwise_max(a, mk2(0.f));
}
__device__ __forceinline__ v2f v2clampx(v2f a) {        // reference l>=2 clamp
  return (v2f){a.x >= 1.f ? 0.99999f : a.x, a.y >= 1.f ? 0.99999f : a.y};
}
__device__ __forceinline__ v2f v2clampc(v2f c) {
  return __builtin_elementwise_min(__builtin_elementwise_max(c, mk2(-0.99999f)),
                                   mk2(0.99999f));
}
__device__ __forceinline__ v2f v2sign(v2f d) {
  return (v2f){(d.x > 0.f) ? 1.f : ((d.x < 0.f) ? -1.f : 0.f),
               (d.y > 0.f) ? 1.f : ((d.y < 0.f) ? -1.f : 0.f)};
}

// theta = 2*asin(x), x in [0,1). Branchless, |err|~1e-5. (validated r2-r11)
__device__ __forceinline__ float theta_from_x(float x) {
  bool big = x > 0.5f;
  float z = big ? fmaf(-0.5f, x, 0.5f) : x * x;
  float s = big ? sqrt_f(z) : x;
  float P = fmaf(z, 0.022371875f, 0.030381944f);
  P = fmaf(z, P, 0.044642857f);
  P = fmaf(z, P, 0.075f);
  P = fmaf(z, P, 0.16666667f);
  float r = fmaf(s * z, P, s);
  return big ? fmaf(-4.f, r, 3.14159265358979f) : 2.f * r;
}
__device__ __forceinline__ v2f v2theta(v2f x) {
  return (v2f){theta_from_x(x.x), theta_from_x(x.y)};
}

// cold path: runtime face recompute, inside-formula accumulate (r11-validated)
__device__ __attribute__((noinline)) void inside_face_rt(
    int f0, int f1, int f2i, const float4* vpos,
    float qx, float qy, float qz, float* wjh)
{
  float4 v0 = vpos[f0], v1 = vpos[f1], v2 = vpos[f2i];
  float a0x = v0.x - qx, a0y = v0.y - qy, a0z = v0.z - qz;
  float a1x = v1.x - qx, a1y = v1.y - qy, a1z = v1.z - qz;
  float a2x = v2.x - qx, a2y = v2.y - qy, a2z = v2.z - qz;
  float ss0 = fmaf(a0x, a0x, fmaf(a0y, a0y, a0z * a0z));
  float ss1 = fmaf(a1x, a1x, fmaf(a1y, a1y, a1z * a1z));
  float ss2 = fmaf(a2x, a2x, fmaf(a2y, a2y, a2z * a2z));
  float i0 = rsq_f(ss0), i1 = rsq_f(ss1), i2 = rsq_f(ss2);
  float d0 = ss0 * i0, d1 = ss1 * i1, d2 = ss2 * i2;
  float u0x = a0x * i0, u0y = a0y * i0, u0z = a0z * i0;
  float u1x = a1x * i1, u1y = a1y * i1, u1z = a1z * i1;
  float u2x = a2x * i2, u2y = a2y * i2, u2z = a2z * i2;
  float ex = u1x - u2x, ey = u1y - u2y, ez = u1z - u2z;
  float x0 = 0.5f * sqrt_f(fmaf(ex, ex, fmaf(ey, ey, ez * ez)));
  ex = u2x - u0x; ey = u2y - u0y; ez = u2z - u0z;
  float x1 = 0.5f * sqrt_f(fmaf(ex, ex, fmaf(ey, ey, ez * ez)));
  ex = u0x - u1x; ey = u0y - u1y; ez = u0z - u1z;
  float x2 = 0.5f * sqrt_f(fmaf(ex, ex, fmaf(ey, ey, ez * ez)));
  if (x0 >= 1.f) x0 = 0.99999f;
  if (x1 >= 1.f) x1 = 0.99999f;
  if (x2 >= 1.f) x2 = 0.99999f;
  float th0 = theta_from_x(x0), th1 = theta_from_x(x1), th2 = theta_from_x(x2);
  float hh = 0.5f * ((th0 + th1) + th2);
  if (3.14159265358979f - hh < 1e-4f) {
    float cx0 = sqrt_f(fmaxf(fmaf(-x0, x0, 1.f), 0.f));
    float cx1 = sqrt_f(fmaxf(fmaf(-x1, x1, 1.f), 0.f));
    float cx2 = sqrt_f(fmaxf(fmaf(-x2, x2, 1.f), 0.f));
    wjh[f0 * WJS]  += (2.f * (x0 * cx0) * d2) * d1;
    wjh[f1 * WJS]  += (2.f * (x1 * cx1) * d0) * d2;
    wjh[f2i * WJS] += (2.f * (x2 * cx2) * d1) * d0;
  }
}

// ---------------- Kernel D: MVC weights + deformed ----------------
// 64 threads = 1 wave; each THREAD owns 2 points (lane, lane+64) computed
// with ext_vector_type(2) arithmetic -> v_pk_* packed FP32 on gfx950.
__global__ __launch_bounds__(64) void mvc_kernel(
    const float* __restrict__ src,      // (B,3,N)
    const float* __restrict__ cage_t,   // (B,42,3)
    const float* __restrict__ ncage_t,  // (B,42,3)
    const int* __restrict__ faces,      // (80,3)
    float* __restrict__ out_def,        // (B,3,N)
    float* __restrict__ out_w)          // (B,N,42)
{
  __shared__ float4 vpos[NV];
  __shared__ float4 npos[NV];
  __shared__ int fidp[NF];
  __shared__ float wj[NV * WJS];       // cols 0..127 = this wave's 128 points

  const float PI_F = 3.14159265358979323846f;
  int lane = threadIdx.x;
  int b    = blockIdx.x / (NP / 128);
  int pblk = blockIdx.x % (NP / 128);
  int gpA  = pblk * 128 + lane;
  int gpB  = gpA + 64;

  if (lane < NV) {
    const float* cp = cage_t + (size_t)b * NV * 3 + lane * 3;
    vpos[lane] = make_float4(cp[0], cp[1], cp[2], 0.f);
    const float* np_ = ncage_t + (size_t)b * NV * 3 + lane * 3;
    npos[lane] = make_float4(np_[0], np_[1], np_[2], 0.f);
  }
  for (int i = lane; i < NF; i += 64) {
    int f0 = faces[3 * i], f1 = faces[3 * i + 1], f2i = faces[3 * i + 2];
    fidp[i] = f0 | (f1 << 6) | (f2i << 12);
  }
  for (int i = lane; i < NV * WJS; i += 64) wj[i] = 0.f;
  __syncthreads();

  v2f qx = (v2f){src[(size_t)b * 3 * NP + gpA],          src[(size_t)b * 3 * NP + gpB]};
  v2f qy = (v2f){src[(size_t)b * 3 * NP + NP + gpA],     src[(size_t)b * 3 * NP + NP + gpB]};
  v2f qz = (v2f){src[(size_t)b * 3 * NP + 2 * NP + gpA], src[(size_t)b * 3 * NP + 2 * NP + gpB]};

  // close-mask hoisted: per-vertex distance check (matches reference dj<1e-8
  // over all 42 vertices; every vertex is in some face)
  unsigned long long clA = 0ull, clB = 0ull;
  for (int c = 0; c < NV; c++) {
    float4 v = vpos[c];
    v2f ax = mk2(v.x) - qx, ay = mk2(v.y) - qy, az = mk2(v.z) - qz;
    v2f ss = v2fma(ax, ax, v2fma(ay, ay, az * az));
    if (ss.x < 1e-16f) clA |= (1ull << c);
    if (ss.y < 1e-16f) clB |= (1ull << c);
  }

  int inA = 0, inB = 0;
  float* wjA = &wj[lane];
  float* wjB = wjA + 64;

  #pragma unroll 1
  for (int i = 0; i < NF; i++) {
    int pk = fidp[i];
    int f0 = pk & 63, f1 = (pk >> 6) & 63, f2i = pk >> 12;
    float4 v0 = vpos[f0], v1 = vpos[f1], v2 = vpos[f2i];
    v2f a0x = mk2(v0.x) - qx, a0y = mk2(v0.y) - qy, a0z = mk2(v0.z) - qz;
    v2f a1x = mk2(v1.x) - qx, a1y = mk2(v1.y) - qy, a1z = mk2(v1.z) - qz;
    v2f a2x = mk2(v2.x) - qx, a2y = mk2(v2.y) - qy, a2z = mk2(v2.z) - qz;
    v2f ss0 = v2fma(a0x, a0x, v2fma(a0y, a0y, a0z * a0z));
    v2f ss1 = v2fma(a1x, a1x, v2fma(a1y, a1y, a1z * a1z));
    v2f ss2 = v2fma(a2x, a2x, v2fma(a2y, a2y, a2z * a2z));
    v2f i0 = v2rsq(ss0), i1 = v2rsq(ss1), i2 = v2rsq(ss2);
    v2f d0 = ss0 * i0, d1 = ss1 * i1, d2 = ss2 * i2;
    v2f u0x = a0x * i0, u0y = a0y * i0, u0z = a0z * i0;
    v2f u1x = a1x * i1, u1y = a1y * i1, u1z = a1z * i1;
    v2f u2x = a2x * i2, u2y = a2y * i2, u2z = a2z * i2;
    // chord half-lengths via EDGE SUBTRACTION (r7 lesson: never 1-u.u')
    v2f ex = u1x - u2x, ey = u1y - u2y, ez = u1z - u2z;
    v2f x0 = mk2(0.5f) * v2sqrt(v2fma(ex, ex, v2fma(ey, ey, ez * ez)));
    ex = u2x - u0x; ey = u2y - u0y; ez = u2z - u0z;
    v2f x1 = mk2(0.5f) * v2sqrt(v2fma(ex, ex, v2fma(ey, ey, ez * ez)));
    ex = u0x - u1x; ey = u0y - u1y; ez = u0z - u1z;
    v2f x2 = mk2(0.5f) * v2sqrt(v2fma(ex, ex, v2fma(ey, ey, ez * ez)));
    x0 = v2clampx(x0); x1 = v2clampx(x1); x2 = v2clampx(x2);
    v2f one = mk2(1.f);
    v2f cx0 = v2sqrt(v2max0(v2fma(-x0, x0, one)));
    v2f cx1 = v2sqrt(v2max0(v2fma(-x1, x1, one)));
    v2f cx2 = v2sqrt(v2max0(v2fma(-x2, x2, one)));
    v2f th0 = v2theta(x0), th1 = v2theta(x1), th2 = v2theta(x2);
    v2f hh = mk2(0.5f) * ((th0 + th1) + th2);
    if (PI_F - hh.x < 1e-4f) inA = 1;
    if (PI_F - hh.y < 1e-4f) inB = 1;
    v2f t0 = x0 * cx0, t1 = x1 * cx1, t2 = x2 * cx2;
    v2f st0 = t0 + t0, st1 = t1 + t1, st2 = t2 + t2;     // sin(theta_i)
    v2f A1 = x0 * (cx1 * cx2);
    v2f A2 = x1 * (cx0 * cx2);
    v2f A3 = x2 * (cx0 * cx1);
    v2f A4 = x0 * (x1 * x2);
    v2f sh  = ((A1 + A2) + A3) - A4;      // sin(h)
    v2f sm0 = ((A2 - A1) + A3) + A4;      // sin(h-th0)
    v2f sm1 = ((A1 - A2) + A3) + A4;      // sin(h-th1)
    v2f sm2 = ((A1 + A2) - A3) + A4;      // sin(h-th2)
    v2f twosh = sh + sh;
    v2f none = mk2(-1.f);
    v2f c0 = v2fma(twosh * sm0, v2rcp(st1 * st2), none);
    v2f c1 = v2fma(twosh * sm1, v2rcp(st2 * st0), none);
    v2f c2 = v2fma(twosh * sm2, v2rcp(st0 * st1), none);
    c0 = v2clampc(c0); c1 = v2clampc(c1); c2 = v2clampc(c2);
    v2f m0 = v2fma(u1y, u2z, -(u1z * u2y));
    v2f m1 = v2fma(u1x, u2z, -(u1z * u2x));
    v2f m2 = v2fma(u1x, u2y, -(u1y * u2x));
    v2f det = (u0x * m0 - u0y * m1) + u0z * m2;
    v2f sg = v2sign(det);
    v2f sn0 = sg * v2sqrt(v2fma(-c0, c0, one));
    v2f sn1 = sg * v2sqrt(v2fma(-c1, c1, one));
    v2f sn2 = sg * v2sqrt(v2fma(-c2, c2, one));
    v2f w0 = v2fma(-c2, th1, v2fma(-c1, th2, th0)) * v2rcp((d0 * st1) * sn2);
    v2f w1 = v2fma(-c0, th2, v2fma(-c2, th0, th1)) * v2rcp((d1 * st2) * sn0);
    v2f w2 = v2fma(-c1, th0, v2fma(-c0, th1, th2)) * v2rcp((d2 * st0) * sn1);
    wjA[f0 * WJS]  += w0.x;  wjB[f0 * WJS]  += w0.y;
    wjA[f1 * WJS]  += w1.x;  wjB[f1 * WJS]  += w1.y;
    wjA[f2i * WJS] += w2.x;  wjB[f2i * WJS] += w2.y;
  }

  // cold paths (per point, scalar; r11-validated)
  if (inA) {
    for (int c = 0; c < NV; c++) wjA[c * WJS] = 0.f;
    for (int i = 0; i < NF; i++) {
      int pk = fidp[i];
      inside_face_rt(pk & 63, (pk >> 6) & 63, pk >> 12, vpos, qx.x, qy.x, qz.x, wjA);
    }
  }
  if (inB) {
    for (int c = 0; c < NV; c++) wjB[c * WJS] = 0.f;
    for (int i = 0; i < NF; i++) {
      int pk = fidp[i];
      inside_face_rt(pk & 63, (pk >> 6) & 63, pk >> 12, vpos, qx.y, qy.y, qz.y, wjB);
    }
  }

  // per-point epilogue (own wave's LDS; no barrier needed)
  auto finish = [&](float* wjh, unsigned long long mCl, int gp) {
    float sum = 0.f;
    if (mCl) {
      for (int c = 0; c < NV; c++) {
        float w = ((mCl >> c) & 1ull) ? 1.f : 0.f;
        wjh[c * WJS] = w;
        sum += w;
      }
    } else {
      for (int c = 0; c < NV; c++) sum += wjh[c * WJS];
    }
    if (sum == 0.f) sum = 1.f;
    float inv = rcp_f(sum);
    float ax = 0.f, ay = 0.f, az = 0.f;
    for (int c = 0; c < NV; c++) {
      float w = wjh[c * WJS] * inv;
      wjh[c * WJS] = w;
      float4 n = npos[c];
      ax = fmaf(w, n.x, ax);
      ay = fmaf(w, n.y, ay);
      az = fmaf(w, n.z, az);
    }
    out_def[(size_t)b * 3 * NP + gp]          = ax;
    out_def[(size_t)b * 3 * NP + NP + gp]     = ay;
    out_def[(size_t)b * 3 * NP + 2 * NP + gp] = az;
  };
  finish(wjA, clA, gpA);
  finish(wjB, clB, gpB);
  __syncthreads();

  // coalesced weight write for the 128 points of this block
  float* wbase = out_w + ((size_t)b * NP + pblk * 128) * NV;
  for (int idx = lane; idx < 128 * NV; idx += 64) {
    int pp = idx / NV;
    int c  = idx - pp * NV;
    wbase[idx] = wj[c * WJS + pp];
  }
}

// ---------------- shared split-K linear body (round-3 proven) ----------------
__device__ __forceinline__ void splitk_body(
    const float* in0, const float* in1,
    const float* W, const float* bias, float* out,
    int FI, int FO, int relu, int ox, int bb, int tid,
    float* sIn, float (*part)[64])
{
  for (int i = tid; i < FI; i += 256) {
    float v;
    if (in1) v = (i < FEAT) ? in0[(size_t)bb * FEAT + i]
                            : in1[(size_t)bb * FEAT + i - FEAT];
    else     v = in0[(size_t)bb * FI + i];
    sIn[i] = v;
  }
  __syncthreads();
  int o = ox * 64 + (tid & 63);
  int kk = tid >> 6;
  int seg = FI >> 2;
  float acc = 0.f;
  const float* wp = W + o;
  #pragma unroll 4
  for (int i = kk * seg; i < (kk + 1) * seg; i++)
    acc = fmaf(sIn[i], wp[(size_t)i * FO], acc);
  part[kk][tid & 63] = acc;
  __syncthreads();
  if (tid < 64) {
    float r = ((part[0][tid] + part[1][tid]) + (part[2][tid] + part[3][tid]))
              + bias[o];
    out[(size_t)bb * FO + o] = relu ? fmaxf(r, 0.f) : r;
  }
}

// ---------------- Kernel A: cage_opt (blocks<672) + L1 split-K (672..799) ----
__global__ __launch_bounds__(256) void cage_l1_kernel(
    const float* __restrict__ tmpl, const float* __restrict__ src,
    const float* __restrict__ sf, const float* __restrict__ tf,
    const float* __restrict__ W1, const float* __restrict__ b1,
    float* __restrict__ cage, float* __restrict__ h1)
{
  __shared__ float red[8];
  __shared__ float sIn[512];
  __shared__ float part[4][64];
  int tid = threadIdx.x;

  if (blockIdx.x < BB * NV) {
    int b = blockIdx.x / NV;
    int v = blockIdx.x % NV;
    const float* sp = src + (size_t)b * 3 * NP;
    float cx = tmpl[v], cy = tmpl[NV + v], cz = tmpl[2 * NV + v];
    int k = 0;
    while (true) {
      float m = 3.4e38f;
      for (int i = tid; i < NP; i += 256) {
        float dx = __fsub_rn(cx, sp[i]);
        float dy = __fsub_rn(cy, sp[NP + i]);
        float dz = __fsub_rn(cz, sp[2 * NP + i]);
        float ss = __fadd_rn(__fadd_rn(__fmul_rn(dx, dx), __fmul_rn(dy, dy)),
                             __fmul_rn(dz, dz));
        m = fminf(m, ss);
      }
      #pragma unroll
      for (int off = 32; off > 0; off >>= 1)
        m = fminf(m, __shfl_down(m, off, 64));
      int wid = tid >> 6;
      __syncthreads();
      if ((tid & 63) == 0) red[wid] = m;
      __syncthreads();
      if (tid == 0) {
        float mm = fminf(fminf(red[0], red[1]), fminf(red[2], red[3]));
        red[4] = sqrtf(mm);
      }
      __syncthreads();
      float mind = red[4];
      if (mind > 0.4f && k < 100) {
        cx = __fsub_rn(cx, __fmul_rn(0.01f, cx));
        cy = __fsub_rn(cy, __fmul_rn(0.01f, cy));
        cz = __fsub_rn(cz, __fmul_rn(0.01f, cz));
        k++;
      } else {
        break;
      }
    }
    if (tid == 0) {
      cage[(size_t)b * 3 * NV + v]          = cx;
      cage[(size_t)b * 3 * NV + NV + v]     = cy;
      cage[(size_t)b * 3 * NV + 2 * NV + v] = cz;
    }
  } else {
    int idx = blockIdx.x - BB * NV;   // 0..127
    splitk_body(sf, tf, W1, b1, h1, 512, 512, 1, idx & 7, idx >> 3,
                tid, sIn, part);
  }
}

// ---------------- standalone split-K linear (round-3 proven) ----------------
__global__ __launch_bounds__(256) void linear_splitk(
    const float* __restrict__ in0, const float* __restrict__ in1,
    const float* __restrict__ W, const float* __restrict__ bias,
    float* __restrict__ out, int FI, int FO, int relu)
{
  __shared__ float sIn[512];
  __shared__ float part[4][64];
  splitk_body(in0, in1, W, bias, out, FI, FO, relu,
              blockIdx.x, blockIdx.y, threadIdx.x, sIn, part);
}

// ---------------- L4 + cage finalize (round-3 proven) ----------------
__global__ __launch_bounds__(128) void l4_finalize_kernel(
    const float* __restrict__ h3,
    const float* __restrict__ W4, const float* __restrict__ b4,
    const float* __restrict__ cage,
    float* __restrict__ out_io,
    float* __restrict__ cage_t,
    float* __restrict__ ncage_t)
{
  __shared__ float sIn[256];
  int bb = blockIdx.x;
  int tid = threadIdx.x;
  sIn[tid] = h3[(size_t)bb * 256 + tid];
  sIn[tid + 128] = h3[(size_t)bb * 256 + tid + 128];
  __syncthreads();
  if (tid < 126) {
    float acc = b4[tid];
    const float* wp = W4 + tid;
    #pragma unroll 4
    for (int i = 0; i < 256; i++) acc = fmaf(sIn[i], wp[(size_t)i * 126], acc);
    out_io[(size_t)bb * 126 + tid] = acc;
    float c  = cage[(size_t)bb * 126 + tid];
    float nc = c + acc;
    int d = tid / NV, v = tid - d * NV;
    cage_t[(size_t)bb * NV * 3 + v * 3 + d]  = c;
    ncage_t[(size_t)bb * NV * 3 + v * 3 + d] = nc;
  }
}

extern "C" void kernel_launch(void* const* d_in, const int* in_sizes, int n_in,
                              void* d_out, int out_size, void* d_ws, size_t ws_size,
                              hipStream_t stream) {
  (void)in_sizes; (void)n_in; (void)out_size; (void)d_ws; (void)ws_size;
  const float* src   = (const float*)d_in[0];
  const float* sf    = (const float*)d_in[2];
  const float* tf    = (const float*)d_in[3];
  const float* tmpl  = (const float*)d_in[4];
  const int*   faces = (const int*)d_in[5];
  const float* W1 = (const float*)d_in[6];  const float* b1 = (const float*)d_in[7];
  const float* W2 = (const float*)d_in[8];  const float* b2 = (const float*)d_in[9];
  const float* W3 = (const float*)d_in[10]; const float* b3 = (const float*)d_in[11];
  const float* W4 = (const float*)d_in[12]; const float* b4 = (const float*)d_in[13];

  float* out = (float*)d_out;
  float* out_cage_t  = out;                 // (16,42,3)   2016
  float* out_ncage_t = out + 2016;          // (16,42,3)   2016
  float* out_def     = out + 4032;          // (16,3,8192) 393216
  float* out_w       = out + 397248;        // (16,8192,42) 5505024
  float* out_io      = out + 5902272;       // (16,126)    2016

  // scratch carved out of the weights region (fully overwritten by mvc_kernel)
  float* s_cage = out_w;           // 2016
  float* s_h1   = out_w + 2016;    // 8192
  float* s_h2   = out_w + 10208;   // 8192
  float* s_h3   = out_w + 18400;   // 4096

  cage_l1_kernel<<<dim3(BB * NV + 128), dim3(256), 0, stream>>>(
      tmpl, src, sf, tf, W1, b1, s_cage, s_h1);
  linear_splitk<<<dim3(8, BB), dim3(256), 0, stream>>>(s_h1, nullptr, W2, b2, s_h2, 512, 512, 1);
  linear_splitk<<<dim3(4, BB), dim3(256), 0, stream>>>(s_h2, nullptr, W3, b3, s_h3, 512, 256, 1);
  l4_finalize_kernel<<<dim3(BB), dim3(128), 0, stream>>>(
      s_h3, W4, b4, s_cage, out_io, out_cage_t, out_ncage_t);
  mvc_kernel<<<dim3(BB * (NP / 128)), dim3(64), 0, stream>>>(
      src, out_cage_t, out_ncage_t, faces, out_def, out_w);
}

// Round 14
// 173.218 us; speedup vs baseline: 1.4954x; 1.0583x over previous
//
#include <hip/hip_runtime.h>
#include <math.h>

#define BB 16
#define NP 8192
#define NV 42
#define NF 80
#define FEAT 256
#define PPB 128          // points per block (mvc)
#define WJS 129          // stride >= 128 columns! (r13 bug: 112 overflowed); odd -> conflict-free

typedef float v2f __attribute__((ext_vector_type(2)));

__device__ __forceinline__ float rcp_f(float x)  { return __builtin_amdgcn_rcpf(x); }
__device__ __forceinline__ float rsq_f(float x)  { return __builtin_amdgcn_rsqf(x); }
__device__ __forceinline__ float sqrt_f(float x) { return __builtin_amdgcn_sqrtf(x); }

__device__ __forceinline__ v2f mk2(float s) { return (v2f){s, s}; }
__device__ __forceinline__ v2f v2fma(v2f a, v2f b, v2f c) {
  return __builtin_elementwise_fma(a, b, c);
}
__device__ __forceinline__ v2f v2sqrt(v2f a) {
  return (v2f){sqrt_f(a.x), sqrt_f(a.y)};
}
__device__ __forceinline__ v2f v2rsq(v2f a) {
  return (v2f){rsq_f(a.x), rsq_f(a.y)};
}
__device__ __forceinline__ v2f v2rcp(v2f a) {
  return (v2f){rcp_f(a.x), rcp_f(a.y)};
}
__device__ __forceinline__ v2f v2max0(v2f a) {
  return __builtin_elementwise_max(a, mk2(0.f));
}
__device__ __forceinline__ v2f v2clampx(v2f a) {        // reference l>=2 clamp
  return (v2f){a.x >= 1.f ? 0.99999f : a.x, a.y >= 1.f ? 0.99999f : a.y};
}
__device__ __forceinline__ v2f v2clampc(v2f c) {
  return __builtin_elementwise_min(__builtin_elementwise_max(c, mk2(-0.99999f)),
                                   mk2(0.99999f));
}
__device__ __forceinline__ v2f v2sign(v2f d) {
  return (v2f){(d.x > 0.f) ? 1.f : ((d.x < 0.f) ? -1.f : 0.f),
               (d.y > 0.f) ? 1.f : ((d.y < 0.f) ? -1.f : 0.f)};
}

// theta = 2*asin(x), x in [0,1). Branchless, |err|~1e-5. (validated r2-r12)
__device__ __forceinline__ float theta_from_x(float x) {
  bool big = x > 0.5f;
  float z = big ? fmaf(-0.5f, x, 0.5f) : x * x;
  float s = big ? sqrt_f(z) : x;
  float P = fmaf(z, 0.022371875f, 0.030381944f);
  P = fmaf(z, P, 0.044642857f);
  P = fmaf(z, P, 0.075f);
  P = fmaf(z, P, 0.16666667f);
  float r = fmaf(s * z, P, s);
  return big ? fmaf(-4.f, r, 3.14159265358979f) : 2.f * r;
}
__device__ __forceinline__ v2f v2theta(v2f x) {
  return (v2f){theta_from_x(x.x), theta_from_x(x.y)};
}

// cold path: runtime face recompute, inside-formula accumulate (r11/r12-validated)
__device__ __attribute__((noinline)) void inside_face_rt(
    int f0, int f1, int f2i, const float4* vpos,
    float qx, float qy, float qz, float* wjh)
{
  float4 v0 = vpos[f0], v1 = vpos[f1], v2 = vpos[f2i];
  float a0x = v0.x - qx, a0y = v0.y - qy, a0z = v0.z - qz;
  float a1x = v1.x - qx, a1y = v1.y - qy, a1z = v1.z - qz;
  float a2x = v2.x - qx, a2y = v2.y - qy, a2z = v2.z - qz;
  float ss0 = fmaf(a0x, a0x, fmaf(a0y, a0y, a0z * a0z));
  float ss1 = fmaf(a1x, a1x, fmaf(a1y, a1y, a1z * a1z));
  float ss2 = fmaf(a2x, a2x, fmaf(a2y, a2y, a2z * a2z));
  float i0 = rsq_f(ss0), i1 = rsq_f(ss1), i2 = rsq_f(ss2);
  float d0 = ss0 * i0, d1 = ss1 * i1, d2 = ss2 * i2;
  float u0x = a0x * i0, u0y = a0y * i0, u0z = a0z * i0;
  float u1x = a1x * i1, u1y = a1y * i1, u1z = a1z * i1;
  float u2x = a2x * i2, u2y = a2y * i2, u2z = a2z * i2;
  float ex = u1x - u2x, ey = u1y - u2y, ez = u1z - u2z;
  float x0 = 0.5f * sqrt_f(fmaf(ex, ex, fmaf(ey, ey, ez * ez)));
  ex = u2x - u0x; ey = u2y - u0y; ez = u2z - u0z;
  float x1 = 0.5f * sqrt_f(fmaf(ex, ex, fmaf(ey, ey, ez * ez)));
  ex = u0x - u1x; ey = u0y - u1y; ez = u0z - u1z;
  float x2 = 0.5f * sqrt_f(fmaf(ex, ex, fmaf(ey, ey, ez * ez)));
  if (x0 >= 1.f) x0 = 0.99999f;
  if (x1 >= 1.f) x1 = 0.99999f;
  if (x2 >= 1.f) x2 = 0.99999f;
  float th0 = theta_from_x(x0), th1 = theta_from_x(x1), th2 = theta_from_x(x2);
  float hh = 0.5f * ((th0 + th1) + th2);
  if (3.14159265358979f - hh < 1e-4f) {
    float cx0 = sqrt_f(fmaxf(fmaf(-x0, x0, 1.f), 0.f));
    float cx1 = sqrt_f(fmaxf(fmaf(-x1, x1, 1.f), 0.f));
    float cx2 = sqrt_f(fmaxf(fmaf(-x2, x2, 1.f), 0.f));
    wjh[f0 * WJS]  += (2.f * (x0 * cx0) * d2) * d1;
    wjh[f1 * WJS]  += (2.f * (x1 * cx1) * d0) * d2;
    wjh[f2i * WJS] += (2.f * (x2 * cx2) * d1) * d0;
  }
}

// ---------------- Kernel D: MVC weights + deformed ----------------
// 128 threads = 2 waves; block owns 128 points. Each thread packs 2 points
// (lane, lane+64) with v2f ext-vector math -> v_pk_* packed FP32 (r12-proven).
// Wave w computes faces [40w,40w+40) into its own LDS region (r8-proven merge).
// 2048 waves total.
__global__ __launch_bounds__(128) void mvc_kernel(
    const float* __restrict__ src,      // (B,3,N)
    const float* __restrict__ cage_t,   // (B,42,3)
    const float* __restrict__ ncage_t,  // (B,42,3)
    const int* __restrict__ faces,      // (80,3)
    float* __restrict__ out_def,        // (B,3,N)
    float* __restrict__ out_w)          // (B,N,42)
{
  __shared__ float4 vpos[NV];
  __shared__ float4 npos[NV];
  __shared__ int fidp[NF];
  __shared__ float wj[2][NV * WJS];
  __shared__ unsigned char insideF[2][PPB];
  __shared__ unsigned int closeLo[PPB];
  __shared__ unsigned int closeHi[PPB];
  __shared__ int blkIn;

  const float PI_F = 3.14159265358979323846f;
  int tid  = threadIdx.x;
  int lane = tid & 63;
  int wv   = tid >> 6;
  int b    = blockIdx.x / (NP / PPB);
  int pblk = blockIdx.x % (NP / PPB);
  int gpA  = pblk * PPB + lane;
  int gpB  = gpA + 64;

  if (tid < NV) {
    const float* cp = cage_t + (size_t)b * NV * 3 + tid * 3;
    vpos[tid] = make_float4(cp[0], cp[1], cp[2], 0.f);
    const float* np_ = ncage_t + (size_t)b * NV * 3 + tid * 3;
    npos[tid] = make_float4(np_[0], np_[1], np_[2], 0.f);
  }
  if (tid < NF) {
    int f0 = faces[3 * tid], f1 = faces[3 * tid + 1], f2i = faces[3 * tid + 2];
    fidp[tid] = f0 | (f1 << 6) | (f2i << 12);
  }
  for (int i = tid; i < 2 * NV * WJS; i += 128) wj[0][i] = 0.f;
  insideF[0][tid] = 0;
  insideF[1][tid] = 0;
  if (tid == 0) blkIn = 0;
  __syncthreads();

  v2f qx = (v2f){src[(size_t)b * 3 * NP + gpA],          src[(size_t)b * 3 * NP + gpB]};
  v2f qy = (v2f){src[(size_t)b * 3 * NP + NP + gpA],     src[(size_t)b * 3 * NP + NP + gpB]};
  v2f qz = (v2f){src[(size_t)b * 3 * NP + 2 * NP + gpA], src[(size_t)b * 3 * NP + 2 * NP + gpB]};

  // close-mask hoist (r12-validated): per-vertex distance check; both waves
  // compute identical masks, wave0 stores them.
  {
    unsigned long long clA = 0ull, clB = 0ull;
    for (int c = 0; c < NV; c++) {
      float4 v = vpos[c];
      v2f ax = mk2(v.x) - qx, ay = mk2(v.y) - qy, az = mk2(v.z) - qz;
      v2f ss = v2fma(ax, ax, v2fma(ay, ay, az * az));
      if (ss.x < 1e-16f) clA |= (1ull << c);
      if (ss.y < 1e-16f) clB |= (1ull << c);
    }
    if (wv == 0) {
      closeLo[lane]      = (unsigned int)clA;
      closeHi[lane]      = (unsigned int)(clA >> 32);
      closeLo[lane + 64] = (unsigned int)clB;
      closeHi[lane + 64] = (unsigned int)(clB >> 32);
    }
  }

  int inA = 0, inB = 0;
  float* wjA = &wj[wv][lane];
  float* wjB = wjA + 64;

  #pragma unroll 1
  for (int i = wv * 40; i < wv * 40 + 40; i++) {
    int pk = fidp[i];
    int f0 = pk & 63, f1 = (pk >> 6) & 63, f2i = pk >> 12;
    float4 v0 = vpos[f0], v1 = vpos[f1], v2 = vpos[f2i];
    v2f a0x = mk2(v0.x) - qx, a0y = mk2(v0.y) - qy, a0z = mk2(v0.z) - qz;
    v2f a1x = mk2(v1.x) - qx, a1y = mk2(v1.y) - qy, a1z = mk2(v1.z) - qz;
    v2f a2x = mk2(v2.x) - qx, a2y = mk2(v2.y) - qy, a2z = mk2(v2.z) - qz;
    v2f ss0 = v2fma(a0x, a0x, v2fma(a0y, a0y, a0z * a0z));
    v2f ss1 = v2fma(a1x, a1x, v2fma(a1y, a1y, a1z * a1z));
    v2f ss2 = v2fma(a2x, a2x, v2fma(a2y, a2y, a2z * a2z));
    v2f i0 = v2rsq(ss0), i1 = v2rsq(ss1), i2 = v2rsq(ss2);
    v2f d0 = ss0 * i0, d1 = ss1 * i1, d2 = ss2 * i2;
    v2f u0x = a0x * i0, u0y = a0y * i0, u0z = a0z * i0;
    v2f u1x = a1x * i1, u1y = a1y * i1, u1z = a1z * i1;
    v2f u2x = a2x * i2, u2y = a2y * i2, u2z = a2z * i2;
    // chord half-lengths via EDGE SUBTRACTION (r7 lesson: never 1-u.u')
    v2f ex = u1x - u2x, ey = u1y - u2y, ez = u1z - u2z;
    v2f x0 = mk2(0.5f) * v2sqrt(v2fma(ex, ex, v2fma(ey, ey, ez * ez)));
    ex = u2x - u0x; ey = u2y - u0y; ez = u2z - u0z;
    v2f x1 = mk2(0.5f) * v2sqrt(v2fma(ex, ex, v2fma(ey, ey, ez * ez)));
    ex = u0x - u1x; ey = u0y - u1y; ez = u0z - u1z;
    v2f x2 = mk2(0.5f) * v2sqrt(v2fma(ex, ex, v2fma(ey, ey, ez * ez)));
    x0 = v2clampx(x0); x1 = v2clampx(x1); x2 = v2clampx(x2);
    v2f one = mk2(1.f);
    v2f cx0 = v2sqrt(v2max0(v2fma(-x0, x0, one)));
    v2f cx1 = v2sqrt(v2max0(v2fma(-x1, x1, one)));
    v2f cx2 = v2sqrt(v2max0(v2fma(-x2, x2, one)));
    v2f th0 = v2theta(x0), th1 = v2theta(x1), th2 = v2theta(x2);
    v2f hh = mk2(0.5f) * ((th0 + th1) + th2);
    if (PI_F - hh.x < 1e-4f) inA = 1;
    if (PI_F - hh.y < 1e-4f) inB = 1;
    v2f t0 = x0 * cx0, t1 = x1 * cx1, t2 = x2 * cx2;
    v2f st0 = t0 + t0, st1 = t1 + t1, st2 = t2 + t2;     // sin(theta_i)
    v2f A1 = x0 * (cx1 * cx2);
    v2f A2 = x1 * (cx0 * cx2);
    v2f A3 = x2 * (cx0 * cx1);
    v2f A4 = x0 * (x1 * x2);
    v2f sh  = ((A1 + A2) + A3) - A4;      // sin(h)
    v2f sm0 = ((A2 - A1) + A3) + A4;      // sin(h-th0)
    v2f sm1 = ((A1 - A2) + A3) + A4;      // sin(h-th1)
    v2f sm2 = ((A1 + A2) - A3) + A4;      // sin(h-th2)
    v2f twosh = sh + sh;
    v2f none = mk2(-1.f);
    v2f c0 = v2fma(twosh * sm0, v2rcp(st1 * st2), none);
    v2f c1 = v2fma(twosh * sm1, v2rcp(st2 * st0), none);
    v2f c2 = v2fma(twosh * sm2, v2rcp(st0 * st1), none);
    c0 = v2clampc(c0); c1 = v2clampc(c1); c2 = v2clampc(c2);
    v2f m0 = v2fma(u1y, u2z, -(u1z * u2y));
    v2f m1 = v2fma(u1x, u2z, -(u1z * u2x));
    v2f m2 = v2fma(u1x, u2y, -(u1y * u2x));
    v2f det = (u0x * m0 - u0y * m1) + u0z * m2;
    v2f sg = v2sign(det);
    v2f sn0 = sg * v2sqrt(v2fma(-c0, c0, one));
    v2f sn1 = sg * v2sqrt(v2fma(-c1, c1, one));
    v2f sn2 = sg * v2sqrt(v2fma(-c2, c2, one));
    v2f w0 = v2fma(-c2, th1, v2fma(-c1, th2, th0)) * v2rcp((d0 * st1) * sn2);
    v2f w1 = v2fma(-c0, th2, v2fma(-c2, th0, th1)) * v2rcp((d1 * st2) * sn0);
    v2f w2 = v2fma(-c1, th0, v2fma(-c0, th1, th2)) * v2rcp((d2 * st0) * sn1);
    wjA[f0 * WJS]  += w0.x;  wjB[f0 * WJS]  += w0.y;
    wjA[f1 * WJS]  += w1.x;  wjB[f1 * WJS]  += w1.y;
    wjA[f2i * WJS] += w2.x;  wjB[f2i * WJS] += w2.y;
  }

  insideF[wv][lane]      = (unsigned char)inA;
  insideF[wv][lane + 64] = (unsigned char)inB;
  if (inA | inB) blkIn = 1;      // benign same-value race
  __syncthreads();

  if (blkIn) {   // cold: exact `where(inside, ...)` semantics (r8-proven merge)
    int mInA = insideF[0][lane]      | insideF[1][lane];
    int mInB = insideF[0][lane + 64] | insideF[1][lane + 64];
    if (mInA) {
      for (int c = 0; c < NV; c++) wjA[c * WJS] = 0.f;
      for (int i = wv * 40; i < wv * 40 + 40; i++) {
        int pk = fidp[i];
        inside_face_rt(pk & 63, (pk >> 6) & 63, pk >> 12, vpos,
                       qx.x, qy.x, qz.x, wjA);
      }
    }
    if (mInB) {
      for (int c = 0; c < NV; c++) wjB[c * WJS] = 0.f;
      for (int i = wv * 40; i < wv * 40 + 40; i++) {
        int pk = fidp[i];
        inside_face_rt(pk & 63, (pk >> 6) & 63, pk >> 12, vpos,
                       qx.y, qy.y, qz.y, wjB);
      }
    }
  }
  __syncthreads();

  // merge halves + finish: thread tid owns point p = tid
  {
    int p = tid;
    unsigned long long mCl =
        (unsigned long long)closeLo[p] |
        ((unsigned long long)closeHi[p] << 32);
    float sum = 0.f;
    for (int c = 0; c < NV; c++) {
      float w = wj[0][c * WJS + p] + wj[1][c * WJS + p];
      if (mCl) w = ((mCl >> c) & 1ull) ? 1.f : 0.f;
      wj[0][c * WJS + p] = w;
      sum += w;
    }
    if (sum == 0.f) sum = 1.f;
    float inv = rcp_f(sum);
    float ax = 0.f, ay = 0.f, az = 0.f;
    for (int c = 0; c < NV; c++) {
      float w = wj[0][c * WJS + p] * inv;
      wj[0][c * WJS + p] = w;
      float4 n = npos[c];
      ax = fmaf(w, n.x, ax);
      ay = fmaf(w, n.y, ay);
      az = fmaf(w, n.z, az);
    }
    int gp = pblk * PPB + p;
    out_def[(size_t)b * 3 * NP + gp]          = ax;
    out_def[(size_t)b * 3 * NP + NP + gp]     = ay;
    out_def[(size_t)b * 3 * NP + 2 * NP + gp] = az;
  }
  __syncthreads();

  // coalesced weight write for the 128 points of this block
  float* wbase = out_w + ((size_t)b * NP + pblk * PPB) * NV;
  for (int idx = tid; idx < PPB * NV; idx += 128) {
    int pp = idx / NV;
    int c  = idx - pp * NV;
    wbase[idx] = wj[0][c * WJS + pp];
  }
}

// ---------------- shared split-K linear body (round-3 proven) ----------------
__device__ __forceinline__ void splitk_body(
    const float* in0, const float* in1,
    const float* W, const float* bias, float* out,
    int FI, int FO, int relu, int ox, int bb, int tid,
    float* sIn, float (*part)[64])
{
  for (int i = tid; i < FI; i += 256) {
    float v;
    if (in1) v = (i < FEAT) ? in0[(size_t)bb * FEAT + i]
                            : in1[(size_t)bb * FEAT + i - FEAT];
    else     v = in0[(size_t)bb * FI + i];
    sIn[i] = v;
  }
  __syncthreads();
  int o = ox * 64 + (tid & 63);
  int kk = tid >> 6;
  int seg = FI >> 2;
  float acc = 0.f;
  const float* wp = W + o;
  #pragma unroll 4
  for (int i = kk * seg; i < (kk + 1) * seg; i++)
    acc = fmaf(sIn[i], wp[(size_t)i * FO], acc);
  part[kk][tid & 63] = acc;
  __syncthreads();
  if (tid < 64) {
    float r = ((part[0][tid] + part[1][tid]) + (part[2][tid] + part[3][tid]))
              + bias[o];
    out[(size_t)bb * FO + o] = relu ? fmaxf(r, 0.f) : r;
  }
}

// ---------------- Kernel A: cage_opt (blocks<672) + L1 split-K (672..799) ----
__global__ __launch_bounds__(256) void cage_l1_kernel(
    const float* __restrict__ tmpl, const float* __restrict__ src,
    const float* __restrict__ sf, const float* __restrict__ tf,
    const float* __restrict__ W1, const float* __restrict__ b1,
    float* __restrict__ cage, float* __restrict__ h1)
{
  __shared__ float red[8];
  __shared__ float sIn[512];
  __shared__ float part[4][64];
  int tid = threadIdx.x;

  if (blockIdx.x < BB * NV) {
    int b = blockIdx.x / NV;
    int v = blockIdx.x % NV;
    const float* sp = src + (size_t)b * 3 * NP;
    float cx = tmpl[v], cy = tmpl[NV + v], cz = tmpl[2 * NV + v];
    int k = 0;
    while (true) {
      float m = 3.4e38f;
      for (int i = tid; i < NP; i += 256) {
        float dx = __fsub_rn(cx, sp[i]);
        float dy = __fsub_rn(cy, sp[NP + i]);
        float dz = __fsub_rn(cz, sp[2 * NP + i]);
        float ss = __fadd_rn(__fadd_rn(__fmul_rn(dx, dx), __fmul_rn(dy, dy)),
                             __fmul_rn(dz, dz));
        m = fminf(m, ss);
      }
      #pragma unroll
      for (int off = 32; off > 0; off >>= 1)
        m = fminf(m, __shfl_down(m, off, 64));
      int wid = tid >> 6;
      __syncthreads();
      if ((tid & 63) == 0) red[wid] = m;
      __syncthreads();
      if (tid == 0) {
        float mm = fminf(fminf(red[0], red[1]), fminf(red[2], red[3]));
        red[4] = sqrtf(mm);
      }
      __syncthreads();
      float mind = red[4];
      if (mind > 0.4f && k < 100) {
        cx = __fsub_rn(cx, __fmul_rn(0.01f, cx));
        cy = __fsub_rn(cy, __fmul_rn(0.01f, cy));
        cz = __fsub_rn(cz, __fmul_rn(0.01f, cz));
        k++;
      } else {
        break;
      }
    }
    if (tid == 0) {
      cage[(size_t)b * 3 * NV + v]          = cx;
      cage[(size_t)b * 3 * NV + NV + v]     = cy;
      cage[(size_t)b * 3 * NV + 2 * NV + v] = cz;
    }
  } else {
    int idx = blockIdx.x - BB * NV;   // 0..127
    splitk_body(sf, tf, W1, b1, h1, 512, 512, 1, idx & 7, idx >> 3,
                tid, sIn, part);
  }
}

// ---------------- standalone split-K linear (round-3 proven) ----------------
__global__ __launch_bounds__(256) void linear_splitk(
    const float* __restrict__ in0, const float* __restrict__ in1,
    const float* __restrict__ W, const float* __restrict__ bias,
    float* __restrict__ out, int FI, int FO, int relu)
{
  __shared__ float sIn[512];
  __shared__ float part[4][64];
  splitk_body(in0, in1, W, bias, out, FI, FO, relu,
              blockIdx.x, blockIdx.y, threadIdx.x, sIn, part);
}

// ---------------- L4 + cage finalize (round-3 proven) ----------------
__global__ __launch_bounds__(128) void l4_finalize_kernel(
    const float* __restrict__ h3,
    const float* __restrict__ W4, const float* __restrict__ b4,
    const float* __restrict__ cage,
    float* __restrict__ out_io,
    float* __restrict__ cage_t,
    float* __restrict__ ncage_t)
{
  __shared__ float sIn[256];
  int bb = blockIdx.x;
  int tid = threadIdx.x;
  sIn[tid] = h3[(size_t)bb * 256 + tid];
  sIn[tid + 128] = h3[(size_t)bb * 256 + tid + 128];
  __syncthreads();
  if (tid < 126) {
    float acc = b4[tid];
    const float* wp = W4 + tid;
    #pragma unroll 4
    for (int i = 0; i < 256; i++) acc = fmaf(sIn[i], wp[(size_t)i * 126], acc);
    out_io[(size_t)bb * 126 + tid] = acc;
    float c  = cage[(size_t)bb * 126 + tid];
    float nc = c + acc;
    int d = tid / NV, v = tid - d * NV;
    cage_t[(size_t)bb * NV * 3 + v * 3 + d]  = c;
    ncage_t[(size_t)bb * NV * 3 + v * 3 + d] = nc;
  }
}

extern "C" void kernel_launch(void* const* d_in, const int* in_sizes, int n_in,
                              void* d_out, int out_size, void* d_ws, size_t ws_size,
                              hipStream_t stream) {
  (void)in_sizes; (void)n_in; (void)out_size; (void)d_ws; (void)ws_size;
  const float* src   = (const float*)d_in[0];
  const float* sf    = (const float*)d_in[2];
  const float* tf    = (const float*)d_in[3];
  const float* tmpl  = (const float*)d_in[4];
  const int*   faces = (const int*)d_in[5];
  const float* W1 = (const float*)d_in[6];  const float* b1 = (const float*)d_in[7];
  const float* W2 = (const float*)d_in[8];  const float* b2 = (const float*)d_in[9];
  const float* W3 = (const float*)d_in[10]; const float* b3 = (const float*)d_in[11];
  const float* W4 = (const float*)d_in[12]; const float* b4 = (const float*)d_in[13];

  float* out = (float*)d_out;
  float* out_cage_t  = out;                 // (16,42,3)   2016
  float* out_ncage_t = out + 2016;          // (16,42,3)   2016
  float* out_def     = out + 4032;          // (16,3,8192) 393216
  float* out_w       = out + 397248;        // (16,8192,42) 5505024
  float* out_io      = out + 5902272;       // (16,126)    2016

  // scratch carved out of the weights region (fully overwritten by mvc_kernel)
  float* s_cage = out_w;           // 2016
  float* s_h1   = out_w + 2016;    // 8192
  float* s_h2   = out_w + 10208;   // 8192
  float* s_h3   = out_w + 18400;   // 4096

  cage_l1_kernel<<<dim3(BB * NV + 128), dim3(256), 0, stream>>>(
      tmpl, src, sf, tf, W1, b1, s_cage, s_h1);
  linear_splitk<<<dim3(8, BB), dim3(256), 0, stream>>>(s_h1, nullptr, W2, b2, s_h2, 512, 512, 1);
  linear_splitk<<<dim3(4, BB), dim3(256), 0, stream>>>(s_h2, nullptr, W3, b3, s_h3, 512, 256, 1);
  l4_finalize_kernel<<<dim3(BB), dim3(128), 0, stream>>>(
      s_h3, W4, b4, s_cage, out_io, out_cage_t, out_ncage_t);
  mvc_kernel<<<dim3(BB * (NP / PPB)), dim3(128), 0, stream>>>(
      src, out_cage_t, out_ncage_t, faces, out_def, out_w);
}

// Round 15
// 159.576 us; speedup vs baseline: 1.6232x; 1.0855x over previous
//
#include <hip/hip_runtime.h>
#include <math.h>

#define BB 16
#define NP 8192
#define NV 42
#define NF 80
#define FEAT 256
#define PPB 64           // points per block (mvc)
#define FH  40           // faces per half-wave
#define WJS 65           // padded LDS stride (65%32==1 -> transposed epilogue conflict-free)

__device__ __forceinline__ float rcp_f(float x)  { return __builtin_amdgcn_rcpf(x); }
__device__ __forceinline__ float rsq_f(float x)  { return __builtin_amdgcn_rsqf(x); }
__device__ __forceinline__ float sqrt_f(float x) { return __builtin_amdgcn_sqrtf(x); }

// theta = 2*asin(x), x in [0,1). Branchless, |err|~1e-5. (validated r2-r14)
__device__ __forceinline__ float theta_from_x(float x) {
  bool big = x > 0.5f;
  float z = big ? fmaf(-0.5f, x, 0.5f) : x * x;
  float s = big ? sqrt_f(z) : x;
  float P = fmaf(z, 0.022371875f, 0.030381944f);
  P = fmaf(z, P, 0.044642857f);
  P = fmaf(z, P, 0.075f);
  P = fmaf(z, P, 0.16666667f);
  float r = fmaf(s * z, P, s);
  return big ? fmaf(-4.f, r, 3.14159265358979f) : 2.f * r;
}

// cold path: runtime face recompute, inside-formula accumulate into private region
__device__ __attribute__((noinline)) void inside_face_rt(
    int f0, int f1, int f2, const float4* vpos,
    float qx, float qy, float qz, float* wjh)   // wjh = &wj[hf*NV*WJS + p]
{
  float4 v0 = vpos[f0], v1 = vpos[f1], v2 = vpos[f2];
  float a0x = v0.x - qx, a0y = v0.y - qy, a0z = v0.z - qz;
  float a1x = v1.x - qx, a1y = v1.y - qy, a1z = v1.z - qz;
  float a2x = v2.x - qx, a2y = v2.y - qy, a2z = v2.z - qz;
  float ss0 = fmaf(a0x, a0x, fmaf(a0y, a0y, a0z * a0z));
  float ss1 = fmaf(a1x, a1x, fmaf(a1y, a1y, a1z * a1z));
  float ss2 = fmaf(a2x, a2x, fmaf(a2y, a2y, a2z * a2z));
  float i0 = rsq_f(ss0), i1 = rsq_f(ss1), i2 = rsq_f(ss2);
  float d0 = ss0 * i0, d1 = ss1 * i1, d2 = ss2 * i2;
  float u0x = a0x * i0, u0y = a0y * i0, u0z = a0z * i0;
  float u1x = a1x * i1, u1y = a1y * i1, u1z = a1z * i1;
  float u2x = a2x * i2, u2y = a2y * i2, u2z = a2z * i2;
  float ex = u1x - u2x, ey = u1y - u2y, ez = u1z - u2z;
  float x0 = 0.5f * sqrt_f(fmaf(ex, ex, fmaf(ey, ey, ez * ez)));
  ex = u2x - u0x; ey = u2y - u0y; ez = u2z - u0z;
  float x1 = 0.5f * sqrt_f(fmaf(ex, ex, fmaf(ey, ey, ez * ez)));
  ex = u0x - u1x; ey = u0y - u1y; ez = u0z - u1z;
  float x2 = 0.5f * sqrt_f(fmaf(ex, ex, fmaf(ey, ey, ez * ez)));
  if (x0 >= 1.f) x0 = 0.99999f;
  if (x1 >= 1.f) x1 = 0.99999f;
  if (x2 >= 1.f) x2 = 0.99999f;
  float th0 = theta_from_x(x0), th1 = theta_from_x(x1), th2 = theta_from_x(x2);
  float hh = 0.5f * ((th0 + th1) + th2);
  if (3.14159265358979f - hh < 1e-4f) {
    float cx0 = sqrt_f(fmaxf(fmaf(-x0, x0, 1.f), 0.f));
    float cx1 = sqrt_f(fmaxf(fmaf(-x1, x1, 1.f), 0.f));
    float cx2 = sqrt_f(fmaxf(fmaf(-x2, x2, 1.f), 0.f));
    wjh[f0 * WJS] += (2.f * (x0 * cx0) * d2) * d1;
    wjh[f1 * WJS] += (2.f * (x1 * cx1) * d0) * d2;
    wjh[f2 * WJS] += (2.f * (x2 * cx2) * d1) * d0;
  }
}

// ---------------- Kernel D: MVC weights + deformed ----------------
// 128 threads: wave0 = faces [0,40) of point p=lane, wave1 = faces [40,80).
// Close-check hoisted to a 42-vertex pre-pass (r12-validated); LDS trimmed
// to 24.1 KB for +1 block/CU residency.
__global__ __launch_bounds__(128) void mvc_kernel(
    const float* __restrict__ src,      // (B,3,N)
    const float* __restrict__ cage_t,   // (B,42,3)
    const float* __restrict__ ncage_t,  // (B,42,3)
    const int* __restrict__ faces,      // (80,3)
    float* __restrict__ out_def,        // (B,3,N)
    float* __restrict__ out_w)          // (B,N,42)
{
  __shared__ float4 vpos[NV];
  __shared__ float4 npos[NV];
  __shared__ int fidp[NF];
  __shared__ float wj[2 * NV * WJS];
  __shared__ unsigned long long closeM1[PPB];
  __shared__ unsigned char insideF[2][PPB];

  const float PI_F = 3.14159265358979323846f;
  int tid = threadIdx.x;
  int p   = tid & (PPB - 1);
  int hf  = tid >> 6;
  int b    = blockIdx.x / (NP / PPB);
  int pblk = blockIdx.x % (NP / PPB);
  int gp   = pblk * PPB + p;

  if (tid < NV) {
    const float* cp = cage_t + (size_t)b * NV * 3 + tid * 3;
    vpos[tid] = make_float4(cp[0], cp[1], cp[2], 0.f);
    const float* np_ = ncage_t + (size_t)b * NV * 3 + tid * 3;
    npos[tid] = make_float4(np_[0], np_[1], np_[2], 0.f);
  }
  if (tid < NF) {
    int f0 = faces[3 * tid], f1 = faces[3 * tid + 1], f2 = faces[3 * tid + 2];
    fidp[tid] = f0 | (f1 << 6) | (f2 << 12);
  }
  for (int i = tid; i < 2 * NV * WJS; i += 128) wj[i] = 0.f;
  __syncthreads();

  float qx = src[(size_t)b * 3 * NP + gp];
  float qy = src[(size_t)b * 3 * NP + NP + gp];
  float qz = src[(size_t)b * 3 * NP + 2 * NP + gp];

  // close-mask hoist (r12-validated): per-vertex distance check covers the
  // reference's dj<1e-8 over all vertices (every vertex is in some face).
  // Both waves compute identical masks; wave0 stores.
  {
    unsigned long long cl = 0ull;
    for (int c = 0; c < NV; c++) {
      float4 v = vpos[c];
      float ax = v.x - qx, ay = v.y - qy, az = v.z - qz;
      float ss = fmaf(ax, ax, fmaf(ay, ay, az * az));
      if (ss < 1e-16f) cl |= (1ull << c);   // d<1e-8 <=> ss<1e-16
    }
    if (hf == 0) closeM1[p] = cl;
  }

  int anyInside = 0;
  float* wjh = wj + hf * (NV * WJS) + p;

  // one face, r8-validated math; independent locals per instantiation
  auto face_eval = [&](int i, int& f0, int& f1, int& f2,
                       float& w0, float& w1, float& w2) {
    int pk = fidp[i];
    f0 = pk & 63; f1 = (pk >> 6) & 63; f2 = pk >> 12;
    float4 v0 = vpos[f0], v1 = vpos[f1], v2 = vpos[f2];
    float a0x = v0.x - qx, a0y = v0.y - qy, a0z = v0.z - qz;
    float a1x = v1.x - qx, a1y = v1.y - qy, a1z = v1.z - qz;
    float a2x = v2.x - qx, a2y = v2.y - qy, a2z = v2.z - qz;
    float ss0 = fmaf(a0x, a0x, fmaf(a0y, a0y, a0z * a0z));
    float ss1 = fmaf(a1x, a1x, fmaf(a1y, a1y, a1z * a1z));
    float ss2 = fmaf(a2x, a2x, fmaf(a2y, a2y, a2z * a2z));
    float i0 = rsq_f(ss0), i1 = rsq_f(ss1), i2 = rsq_f(ss2);
    float d0 = ss0 * i0, d1 = ss1 * i1, d2 = ss2 * i2;
    float u0x = a0x * i0, u0y = a0y * i0, u0z = a0z * i0;
    float u1x = a1x * i1, u1y = a1y * i1, u1z = a1z * i1;
    float u2x = a2x * i2, u2y = a2y * i2, u2z = a2z * i2;
    // chord half-lengths via EDGE SUBTRACTION (r7 lesson: never 1-u.u')
    float ex = u1x - u2x, ey = u1y - u2y, ez = u1z - u2z;
    float x0 = 0.5f * sqrt_f(fmaf(ex, ex, fmaf(ey, ey, ez * ez)));
    ex = u2x - u0x; ey = u2y - u0y; ez = u2z - u0z;
    float x1 = 0.5f * sqrt_f(fmaf(ex, ex, fmaf(ey, ey, ez * ez)));
    ex = u0x - u1x; ey = u0y - u1y; ez = u0z - u1z;
    float x2 = 0.5f * sqrt_f(fmaf(ex, ex, fmaf(ey, ey, ez * ez)));
    if (x0 >= 1.f) x0 = 0.99999f;     // reference clamp l>=2 -> 1.99998
    if (x1 >= 1.f) x1 = 0.99999f;
    if (x2 >= 1.f) x2 = 0.99999f;
    float cx0 = sqrt_f(fmaxf(fmaf(-x0, x0, 1.f), 0.f));
    float cx1 = sqrt_f(fmaxf(fmaf(-x1, x1, 1.f), 0.f));
    float cx2 = sqrt_f(fmaxf(fmaf(-x2, x2, 1.f), 0.f));
    float th0 = theta_from_x(x0);
    float th1 = theta_from_x(x1);
    float th2 = theta_from_x(x2);
    float hh = 0.5f * ((th0 + th1) + th2);
    if (PI_F - hh < 1e-4f) anyInside = 1;
    float t0 = x0 * cx0, t1 = x1 * cx1, t2 = x2 * cx2;
    float st0 = t0 + t0, st1 = t1 + t1, st2 = t2 + t2;   // sin(theta_i)
    float A1 = x0 * (cx1 * cx2);
    float A2 = x1 * (cx0 * cx2);
    float A3 = x2 * (cx0 * cx1);
    float A4 = x0 * (x1 * x2);
    float sh  = ((A1 + A2) + A3) - A4;     // sin(h)
    float sm0 = ((-A1 + A2) + A3) + A4;    // sin(h-th0)
    float sm1 = ((A1 - A2) + A3) + A4;
    float sm2 = ((A1 + A2) - A3) + A4;
    float twosh = sh + sh;
    float c0 = fmaf(twosh * sm0, rcp_f(st1 * st2), -1.f);
    float c1 = fmaf(twosh * sm1, rcp_f(st2 * st0), -1.f);
    float c2 = fmaf(twosh * sm2, rcp_f(st0 * st1), -1.f);
    c0 = fminf(fmaxf(c0, -0.99999f), 0.99999f);
    c1 = fminf(fmaxf(c1, -0.99999f), 0.99999f);
    c2 = fminf(fmaxf(c2, -0.99999f), 0.99999f);
    float det = u0x * fmaf(u1y, u2z, -(u1z * u2y))
              - u0y * fmaf(u1x, u2z, -(u1z * u2x))
              + u0z * fmaf(u1x, u2y, -(u1y * u2x));
    float sg = (det > 0.f) ? 1.f : ((det < 0.f) ? -1.f : 0.f);
    float sn0 = sg * sqrt_f(fmaf(-c0, c0, 1.f));
    float sn1 = sg * sqrt_f(fmaf(-c1, c1, 1.f));
    float sn2 = sg * sqrt_f(fmaf(-c2, c2, 1.f));
    w0 = fmaf(-c2, th1, fmaf(-c1, th2, th0)) * rcp_f((d0 * st1) * sn2);
    w1 = fmaf(-c0, th2, fmaf(-c2, th0, th1)) * rcp_f((d1 * st2) * sn0);
    w2 = fmaf(-c1, th0, fmaf(-c0, th1, th2)) * rcp_f((d2 * st0) * sn1);
  };

  #pragma unroll 1
  for (int j = 0; j < FH / 2; j++) {      // two independent chains per iter
    int fa0, fa1, fa2, fb0, fb1, fb2;
    float wa0, wa1, wa2, wb0, wb1, wb2;
    face_eval(hf * FH + j,            fa0, fa1, fa2, wa0, wa1, wa2);
    face_eval(hf * FH + FH / 2 + j,   fb0, fb1, fb2, wb0, wb1, wb2);
    wjh[fa0 * WJS] += wa0;
    wjh[fa1 * WJS] += wa1;
    wjh[fa2 * WJS] += wa2;
    wjh[fb0 * WJS] += wb0;
    wjh[fb1 * WJS] += wb1;
    wjh[fb2 * WJS] += wb2;
  }

  insideF[hf][p] = (unsigned char)anyInside;
  __syncthreads();

  int mIn = insideF[0][p] | insideF[1][p];
  unsigned long long mCl = closeM1[p];

  if (mIn) {   // cold: exact `where(inside, ...)` semantics
    for (int c = 0; c < NV; c++) wjh[c * WJS] = 0.f;
    #pragma unroll 1
    for (int i = hf * FH; i < hf * FH + FH; i++) {
      int pk = fidp[i];
      inside_face_rt(pk & 63, (pk >> 6) & 63, pk >> 12, vpos, qx, qy, qz, wjh);
    }
  }
  __syncthreads();

  if (tid < PPB) {
    float sum = 0.f;
    for (int c = 0; c < NV; c++) {
      float w = wj[c * WJS + p] + wj[(NV + c) * WJS + p];
      if (mCl) w = ((mCl >> c) & 1ull) ? 1.f : 0.f;
      wj[c * WJS + p] = w;
      sum += w;
    }
    if (sum == 0.f) sum = 1.f;
    float inv = rcp_f(sum);
    float ax = 0.f, ay = 0.f, az = 0.f;
    for (int c = 0; c < NV; c++) {
      float w = wj[c * WJS + p] * inv;
      wj[c * WJS + p] = w;
      float4 n = npos[c];
      ax = fmaf(w, n.x, ax);
      ay = fmaf(w, n.y, ay);
      az = fmaf(w, n.z, az);
    }
    out_def[(size_t)b * 3 * NP + gp]          = ax;
    out_def[(size_t)b * 3 * NP + NP + gp]     = ay;
    out_def[(size_t)b * 3 * NP + 2 * NP + gp] = az;
  }
  __syncthreads();

  // coalesced weight write; stride 65 -> conflict-free transposed read
  float* wbase = out_w + ((size_t)b * NP + pblk * PPB) * NV;
  for (int idx = tid; idx < PPB * NV; idx += 128) {
    int pp = idx / NV;
    int c  = idx - pp * NV;
    wbase[idx] = wj[c * WJS + pp];
  }
}

// ---------------- shared split-K linear body (round-3 proven) ----------------
__device__ __forceinline__ void splitk_body(
    const float* in0, const float* in1,
    const float* W, const float* bias, float* out,
    int FI, int FO, int relu, int ox, int bb, int tid,
    float* sIn, float (*part)[64])
{
  for (int i = tid; i < FI; i += 256) {
    float v;
    if (in1) v = (i < FEAT) ? in0[(size_t)bb * FEAT + i]
                            : in1[(size_t)bb * FEAT + i - FEAT];
    else     v = in0[(size_t)bb * FI + i];
    sIn[i] = v;
  }
  __syncthreads();
  int o = ox * 64 + (tid & 63);
  int kk = tid >> 6;
  int seg = FI >> 2;
  float acc = 0.f;
  const float* wp = W + o;
  #pragma unroll 4
  for (int i = kk * seg; i < (kk + 1) * seg; i++)
    acc = fmaf(sIn[i], wp[(size_t)i * FO], acc);
  part[kk][tid & 63] = acc;
  __syncthreads();
  if (tid < 64) {
    float r = ((part[0][tid] + part[1][tid]) + (part[2][tid] + part[3][tid]))
              + bias[o];
    out[(size_t)bb * FO + o] = relu ? fmaxf(r, 0.f) : r;
  }
}

// ---------------- Kernel A: cage_opt (blocks<672) + L1 split-K (672..799) ----
__global__ __launch_bounds__(256) void cage_l1_kernel(
    const float* __restrict__ tmpl, const float* __restrict__ src,
    const float* __restrict__ sf, const float* __restrict__ tf,
    const float* __restrict__ W1, const float* __restrict__ b1,
    float* __restrict__ cage, float* __restrict__ h1)
{
  __shared__ float red[8];
  __shared__ float sIn[512];
  __shared__ float part[4][64];
  int tid = threadIdx.x;

  if (blockIdx.x < BB * NV) {
    int b = blockIdx.x / NV;
    int v = blockIdx.x % NV;
    const float* sp = src + (size_t)b * 3 * NP;
    float cx = tmpl[v], cy = tmpl[NV + v], cz = tmpl[2 * NV + v];
    int k = 0;
    while (true) {
      float m = 3.4e38f;
      for (int i = tid; i < NP; i += 256) {
        float dx = __fsub_rn(cx, sp[i]);
        float dy = __fsub_rn(cy, sp[NP + i]);
        float dz = __fsub_rn(cz, sp[2 * NP + i]);
        float ss = __fadd_rn(__fadd_rn(__fmul_rn(dx, dx), __fmul_rn(dy, dy)),
                             __fmul_rn(dz, dz));
        m = fminf(m, ss);
      }
      #pragma unroll
      for (int off = 32; off > 0; off >>= 1)
        m = fminf(m, __shfl_down(m, off, 64));
      int wid = tid >> 6;
      __syncthreads();
      if ((tid & 63) == 0) red[wid] = m;
      __syncthreads();
      if (tid == 0) {
        float mm = fminf(fminf(red[0], red[1]), fminf(red[2], red[3]));
        red[4] = sqrtf(mm);
      }
      __syncthreads();
      float mind = red[4];
      if (mind > 0.4f && k < 100) {
        cx = __fsub_rn(cx, __fmul_rn(0.01f, cx));
        cy = __fsub_rn(cy, __fmul_rn(0.01f, cy));
        cz = __fsub_rn(cz, __fmul_rn(0.01f, cz));
        k++;
      } else {
        break;
      }
    }
    if (tid == 0) {
      cage[(size_t)b * 3 * NV + v]          = cx;
      cage[(size_t)b * 3 * NV + NV + v]     = cy;
      cage[(size_t)b * 3 * NV + 2 * NV + v] = cz;
    }
  } else {
    int idx = blockIdx.x - BB * NV;   // 0..127
    splitk_body(sf, tf, W1, b1, h1, 512, 512, 1, idx & 7, idx >> 3,
                tid, sIn, part);
  }
}

// ---------------- standalone split-K linear (round-3 proven) ----------------
__global__ __launch_bounds__(256) void linear_splitk(
    const float* __restrict__ in0, const float* __restrict__ in1,
    const float* __restrict__ W, const float* __restrict__ bias,
    float* __restrict__ out, int FI, int FO, int relu)
{
  __shared__ float sIn[512];
  __shared__ float part[4][64];
  splitk_body(in0, in1, W, bias, out, FI, FO, relu,
              blockIdx.x, blockIdx.y, threadIdx.x, sIn, part);
}

// ---------------- L4 + cage finalize (round-3 proven) ----------------
__global__ __launch_bounds__(128) void l4_finalize_kernel(
    const float* __restrict__ h3,
    const float* __restrict__ W4, const float* __restrict__ b4,
    const float* __restrict__ cage,
    float* __restrict__ out_io,
    float* __restrict__ cage_t,
    float* __restrict__ ncage_t)
{
  __shared__ float sIn[256];
  int bb = blockIdx.x;
  int tid = threadIdx.x;
  sIn[tid] = h3[(size_t)bb * 256 + tid];
  sIn[tid + 128] = h3[(size_t)bb * 256 + tid + 128];
  __syncthreads();
  if (tid < 126) {
    float acc = b4[tid];
    const float* wp = W4 + tid;
    #pragma unroll 4
    for (int i = 0; i < 256; i++) acc = fmaf(sIn[i], wp[(size_t)i * 126], acc);
    out_io[(size_t)bb * 126 + tid] = acc;
    float c  = cage[(size_t)bb * 126 + tid];
    float nc = c + acc;
    int d = tid / NV, v = tid - d * NV;
    cage_t[(size_t)bb * NV * 3 + v * 3 + d]  = c;
    ncage_t[(size_t)bb * NV * 3 + v * 3 + d] = nc;
  }
}

extern "C" void kernel_launch(void* const* d_in, const int* in_sizes, int n_in,
                              void* d_out, int out_size, void* d_ws, size_t ws_size,
                              hipStream_t stream) {
  (void)in_sizes; (void)n_in; (void)out_size; (void)d_ws; (void)ws_size;
  const float* src   = (const float*)d_in[0];
  const float* sf    = (const float*)d_in[2];
  const float* tf    = (const float*)d_in[3];
  const float* tmpl  = (const float*)d_in[4];
  const int*   faces = (const int*)d_in[5];
  const float* W1 = (const float*)d_in[6];  const float* b1 = (const float*)d_in[7];
  const float* W2 = (const float*)d_in[8];  const float* b2 = (const float*)d_in[9];
  const float* W3 = (const float*)d_in[10]; const float* b3 = (const float*)d_in[11];
  const float* W4 = (const float*)d_in[12]; const float* b4 = (const float*)d_in[13];

  float* out = (float*)d_out;
  float* out_cage_t  = out;                 // (16,42,3)   2016
  float* out_ncage_t = out + 2016;          // (16,42,3)   2016
  float* out_def     = out + 4032;          // (16,3,8192) 393216
  float* out_w       = out + 397248;        // (16,8192,42) 5505024
  float* out_io      = out + 5902272;       // (16,126)    2016

  // scratch carved out of the weights region (fully overwritten by mvc_kernel)
  float* s_cage = out_w;           // 2016
  float* s_h1   = out_w + 2016;    // 8192
  float* s_h2   = out_w + 10208;   // 8192
  float* s_h3   = out_w + 18400;   // 4096

  cage_l1_kernel<<<dim3(BB * NV + 128), dim3(256), 0, stream>>>(
      tmpl, src, sf, tf, W1, b1, s_cage, s_h1);
  linear_splitk<<<dim3(8, BB), dim3(256), 0, stream>>>(s_h1, nullptr, W2, b2, s_h2, 512, 512, 1);
  linear_splitk<<<dim3(4, BB), dim3(256), 0, stream>>>(s_h2, nullptr, W3, b3, s_h3, 512, 256, 1);
  l4_finalize_kernel<<<dim3(BB), dim3(128), 0, stream>>>(
      s_h3, W4, b4, s_cage, out_io, out_cage_t, out_ncage_t);
  mvc_kernel<<<dim3(BB * (NP / PPB)), dim3(128), 0, stream>>>(
      src, out_cage_t, out_ncage_t, faces, out_def, out_w);
}